// Round 2
// baseline (381.629 us; speedup 1.0000x reference)
//
#include <hip/hip_runtime.h>
#include <hip/hip_bf16.h>

// Problem: N=64 batches, IO=64, H=1024, S=512
#define IOdim 64
#define Hdim  1024
#define Sdim  512
#define Nbat  64

typedef __bf16 bf16x8_t __attribute__((ext_vector_type(8)));
typedef float  f32x4_t  __attribute__((ext_vector_type(4)));

#define MFMA16(a, b, c) __builtin_amdgcn_mfma_f32_16x16x32_bf16((a), (b), (c), 0, 0, 0)

__device__ __forceinline__ unsigned short f2bf(float f) {
    return __builtin_bit_cast(unsigned short, (__bf16)f);
}
__device__ __forceinline__ bf16x8_t cvt8(float4 p0, float4 p1) {
    bf16x8_t b;
    b[0] = (__bf16)p0.x; b[1] = (__bf16)p0.y; b[2] = (__bf16)p0.z; b[3] = (__bf16)p0.w;
    b[4] = (__bf16)p1.x; b[5] = (__bf16)p1.y; b[6] = (__bf16)p1.z; b[7] = (__bf16)p1.w;
    return b;
}

// ---------------------------------------------------------------------------
// Prep: fp32 -> bf16 elementwise (output_set, 65536 elems)
__global__ __launch_bounds__(256) void cvt_kernel(const float* __restrict__ in,
                                                  unsigned short* __restrict__ outp,
                                                  int nElem) {
    int idx = blockIdx.x * 256 + threadIdx.x;
    if (idx < nElem) outp[idx] = f2bf(in[idx]);
}

// Prep: transpose fp32 [R][C] -> bf16 [C][R] (LDS 32x32 tiles)
__global__ __launch_bounds__(256) void transpose_cvt(const float* __restrict__ in,
                                                     unsigned short* __restrict__ outp,
                                                     int R, int C) {
    __shared__ float tile[32][33];
    int c0 = blockIdx.x * 32, r0 = blockIdx.y * 32;
    int tx = threadIdx.x, ty = threadIdx.y; // 32 x 8
#pragma unroll
    for (int i = 0; i < 4; i++) {
        int r = ty + i * 8;
        tile[r][tx] = in[(size_t)(r0 + r) * C + c0 + tx];
    }
    __syncthreads();
#pragma unroll
    for (int i = 0; i < 4; i++) {
        int r = ty + i * 8;
        outp[(size_t)(c0 + r) * R + r0 + tx] = f2bf(tile[tx][r]);
    }
}

// ---------------------------------------------------------------------------
// scores: attn[n][i][s] = sum_h output_set[i][h] * states[n][s][h]
// Barrier-free / LDS-free: A fragments (osb, 128 KB, L1/L2-resident) and
// B fragments (states fp32, converted inline) loaded directly from global.
// Block = 4 waves, s-tile 64 (wave -> 16 s), all 64 i.
__global__ __launch_bounds__(256) void scores_kernel(const float* __restrict__ states,
                                                     const unsigned short* __restrict__ osb,
                                                     float* __restrict__ attnf) {
    int n = blockIdx.y;
    int tid = threadIdx.x, lane = tid & 63, g = tid >> 6;
    int col = lane & 15, quad = lane >> 4;
    int s = blockIdx.x * 64 + g * 16 + col;
    const float* srow = states + (size_t)(n * Sdim + s) * Hdim + quad * 8;
    const unsigned short* ap = osb + (size_t)col * Hdim + quad * 8;
    f32x4_t acc0 = {0,0,0,0}, acc1 = {0,0,0,0}, acc2 = {0,0,0,0}, acc3 = {0,0,0,0};
    for (int kc = 0; kc < Hdim; kc += 32) {
        float4 p0 = *(const float4*)(srow + kc);
        float4 p1 = *(const float4*)(srow + kc + 4);
        bf16x8_t b  = cvt8(p0, p1);
        bf16x8_t a0 = *(const bf16x8_t*)(ap + kc);
        bf16x8_t a1 = *(const bf16x8_t*)(ap + 16 * Hdim + kc);
        bf16x8_t a2 = *(const bf16x8_t*)(ap + 32 * Hdim + kc);
        bf16x8_t a3 = *(const bf16x8_t*)(ap + 48 * Hdim + kc);
        acc0 = MFMA16(a0, b, acc0);
        acc1 = MFMA16(a1, b, acc1);
        acc2 = MFMA16(a2, b, acc2);
        acc3 = MFMA16(a3, b, acc3);
    }
    f32x4_t accs[4] = {acc0, acc1, acc2, acc3};
    float* ob = attnf + (size_t)(n * IOdim) * Sdim + blockIdx.x * 64 + g * 16 + col;
#pragma unroll
    for (int ai = 0; ai < 4; ai++)
#pragma unroll
        for (int r = 0; r < 4; r++) {
            int i = ai * 16 + quad * 4 + r;
            ob[i * Sdim] = accs[ai][r];
        }
}

// ---------------------------------------------------------------------------
// softmax over s (512) per row; writes bf16 attn. 1 wave per row.
__global__ __launch_bounds__(256) void softmax_kernel(const float* __restrict__ attnf,
                                                      unsigned short* __restrict__ attnb) {
    int row = blockIdx.x * 4 + (threadIdx.x >> 6);
    int lane = threadIdx.x & 63;
    const float* p = attnf + (size_t)row * Sdim + lane * 8;
    float4 v0 = ((const float4*)p)[0];
    float4 v1 = ((const float4*)p)[1];
    float v[8] = {v0.x, v0.y, v0.z, v0.w, v1.x, v1.y, v1.z, v1.w};
    float m = v[0];
#pragma unroll
    for (int j = 1; j < 8; j++) m = fmaxf(m, v[j]);
#pragma unroll
    for (int off = 32; off > 0; off >>= 1) m = fmaxf(m, __shfl_xor(m, off));
    float sum = 0.f;
#pragma unroll
    for (int j = 0; j < 8; j++) { v[j] = __expf(v[j] - m); sum += v[j]; }
#pragma unroll
    for (int off = 32; off > 0; off >>= 1) sum += __shfl_xor(sum, off);
    float inv = 1.0f / sum;
    union { unsigned short u[8]; uint4 q; } res;
#pragma unroll
    for (int j = 0; j < 8; j++) res.u[j] = f2bf(v[j] * inv);
    *(uint4*)(attnb + (size_t)row * Sdim + lane * 8) = res.q;
}

// ---------------------------------------------------------------------------
// mix[n][i][h] = sum_s attn[n][i][s] * states[n][s][h]
// LDS only for the statesT chunk (transpose is unavoidable: contraction index
// s is the major axis of states). 64-s chunks -> 8 barrier pairs total.
// attn A-fragments direct from global (attnb n-slice = 64 KB, L1/L2-resident).
__global__ __launch_bounds__(256) void mix_kernel(const float* __restrict__ states,
                                                  const unsigned short* __restrict__ attnb,
                                                  unsigned short* __restrict__ mixb) {
    __shared__ unsigned short Tlds[64 * 72]; // [h 64][s 64] stride 72
    int n = blockIdx.y, h0 = blockIdx.x * 64;
    int tid = threadIdx.x, lane = tid & 63, g = tid >> 6;
    int col = lane & 15, quad = lane >> 4;
    f32x4_t acc0 = {0,0,0,0}, acc1 = {0,0,0,0}, acc2 = {0,0,0,0}, acc3 = {0,0,0,0};
    const unsigned short* ap = attnb + (size_t)(n * IOdim + col) * Sdim + quad * 8;
    for (int sc = 0; sc < Sdim; sc += 64) {
        // stage statesT chunk: thread reads 16 s-rows at h=h0+lane (coalesced 256B),
        // packs two 16B LDS writes at T[lane][g*16 .. +15]
        union { unsigned short u[16]; uint4 q[2]; } pk;
        const float* sp = states + (size_t)(n * Sdim + sc + g * 16) * Hdim + h0 + lane;
#pragma unroll
        for (int rep = 0; rep < 16; rep++) pk.u[rep] = f2bf(sp[(size_t)rep * Hdim]);
        if (sc) __syncthreads(); // prev chunk's readers done before overwrite
        *(uint4*)(Tlds + lane * 72 + g * 16)     = pk.q[0];
        *(uint4*)(Tlds + lane * 72 + g * 16 + 8) = pk.q[1];
        __syncthreads();
#pragma unroll
        for (int ks = 0; ks < 64; ks += 32) {
            bf16x8_t b  = *(const bf16x8_t*)(Tlds + (g * 16 + col) * 72 + ks + quad * 8);
            bf16x8_t a0 = *(const bf16x8_t*)(ap + sc + ks);
            bf16x8_t a1 = *(const bf16x8_t*)(ap + 16 * Sdim + sc + ks);
            bf16x8_t a2 = *(const bf16x8_t*)(ap + 32 * Sdim + sc + ks);
            bf16x8_t a3 = *(const bf16x8_t*)(ap + 48 * Sdim + sc + ks);
            acc0 = MFMA16(a0, b, acc0);
            acc1 = MFMA16(a1, b, acc1);
            acc2 = MFMA16(a2, b, acc2);
            acc3 = MFMA16(a3, b, acc3);
        }
    }
    f32x4_t accs[4] = {acc0, acc1, acc2, acc3};
    int h = h0 + g * 16 + col;
#pragma unroll
    for (int ai = 0; ai < 4; ai++)
#pragma unroll
        for (int r = 0; r < 4; r++) {
            int i = ai * 16 + quad * 4 + r;
            mixb[(size_t)(n * IOdim + i) * Hdim + h] = f2bf(accs[ai][r]);
        }
}

// ---------------------------------------------------------------------------
// o[r][h] = sum_{k<1024} mix[r][k]*Wo[k][h] + sum_k outset[r%64][k]*Wo[1024+k][h] + bo[h]
// t = tanh(o). Barrier-free/LDS-free: A and B fragments direct from global.
// Block: r-tile 64 x h-tile 128 (wave -> 2x16 h cols), 8 MFMA per 6 loads.
__global__ __launch_bounds__(256) void out_gemm(const unsigned short* __restrict__ mixb,
                                                const unsigned short* __restrict__ osb,
                                                const unsigned short* __restrict__ woT,
                                                const float* __restrict__ bo,
                                                unsigned short* __restrict__ tb) {
    int h0 = blockIdx.x * 128, r0 = blockIdx.y * 64;
    int tid = threadIdx.x, lane = tid & 63, g = tid >> 6;
    int col = lane & 15, quad = lane >> 4;
    f32x4_t accA0 = {0,0,0,0}, accA1 = {0,0,0,0}, accA2 = {0,0,0,0}, accA3 = {0,0,0,0};
    f32x4_t accB0 = {0,0,0,0}, accB1 = {0,0,0,0}, accB2 = {0,0,0,0}, accB3 = {0,0,0,0};
    int h1 = h0 + g * 16 + col, h2 = h1 + 64;
    const unsigned short* brow0 = woT + (size_t)h1 * 2048 + quad * 8;
    const unsigned short* brow1 = woT + (size_t)h2 * 2048 + quad * 8;
    const unsigned short* am = mixb + (size_t)(r0 + col) * Hdim + quad * 8;
    const unsigned short* ao = osb + (size_t)col * Hdim + quad * 8;
    for (int kc = 0; kc < 2048; kc += 32) {
        const unsigned short* abase = (kc < 1024) ? (am + kc) : (ao + (kc - 1024));
        bf16x8_t a0 = *(const bf16x8_t*)(abase);
        bf16x8_t a1 = *(const bf16x8_t*)(abase + 16 * Hdim);
        bf16x8_t a2 = *(const bf16x8_t*)(abase + 32 * Hdim);
        bf16x8_t a3 = *(const bf16x8_t*)(abase + 48 * Hdim);
        bf16x8_t b0 = *(const bf16x8_t*)(brow0 + kc);
        bf16x8_t b1 = *(const bf16x8_t*)(brow1 + kc);
        accA0 = MFMA16(a0, b0, accA0);
        accA1 = MFMA16(a1, b0, accA1);
        accA2 = MFMA16(a2, b0, accA2);
        accA3 = MFMA16(a3, b0, accA3);
        accB0 = MFMA16(a0, b1, accB0);
        accB1 = MFMA16(a1, b1, accB1);
        accB2 = MFMA16(a2, b1, accB2);
        accB3 = MFMA16(a3, b1, accB3);
    }
    f32x4_t accsA[4] = {accA0, accA1, accA2, accA3};
    f32x4_t accsB[4] = {accB0, accB1, accB2, accB3};
    float bo1 = bo[h1], bo2 = bo[h2];
#pragma unroll
    for (int ai = 0; ai < 4; ai++)
#pragma unroll
        for (int r = 0; r < 4; r++) {
            int rr = r0 + ai * 16 + quad * 4 + r;
            tb[(size_t)rr * Hdim + h1] = f2bf(tanhf(accsA[ai][r] + bo1));
            tb[(size_t)rr * Hdim + h2] = f2bf(tanhf(accsB[ai][r] + bo2));
        }
}

// ---------------------------------------------------------------------------
// final: partial[blk][n][j] = sum_{k in 256-chunk} t[n][k] * Wc[k][j]
// 256 blocks split K=65536. Barrier-free/LDS-free.
__global__ __launch_bounds__(256) void final_gemm(const unsigned short* __restrict__ tb,
                                                  const unsigned short* __restrict__ wcT,
                                                  float* __restrict__ partials) {
    int kc0 = blockIdx.x * 256;
    int tid = threadIdx.x, lane = tid & 63, g = tid >> 6;
    int col = lane & 15, quad = lane >> 4;
    f32x4_t acc0 = {0,0,0,0}, acc1 = {0,0,0,0}, acc2 = {0,0,0,0}, acc3 = {0,0,0,0};
    const unsigned short* ap = tb + (size_t)col * 65536 + kc0 + quad * 8;
    const unsigned short* bp = wcT + (size_t)(g * 16 + col) * 65536 + kc0 + quad * 8;
    for (int kc = 0; kc < 256; kc += 32) {
        bf16x8_t b  = *(const bf16x8_t*)(bp + kc);
        bf16x8_t a0 = *(const bf16x8_t*)(ap + kc);
        bf16x8_t a1 = *(const bf16x8_t*)(ap + (size_t)16 * 65536 + kc);
        bf16x8_t a2 = *(const bf16x8_t*)(ap + (size_t)32 * 65536 + kc);
        bf16x8_t a3 = *(const bf16x8_t*)(ap + (size_t)48 * 65536 + kc);
        acc0 = MFMA16(a0, b, acc0);
        acc1 = MFMA16(a1, b, acc1);
        acc2 = MFMA16(a2, b, acc2);
        acc3 = MFMA16(a3, b, acc3);
    }
    f32x4_t accs[4] = {acc0, acc1, acc2, acc3};
    int j = g * 16 + col;
    float* pb = partials + blockIdx.x * 4096;
#pragma unroll
    for (int ai = 0; ai < 4; ai++)
#pragma unroll
        for (int r = 0; r < 4; r++) {
            int nn = ai * 16 + quad * 4 + r;
            pb[nn * 64 + j] = accs[ai][r];
        }
}

// reduce 256 partials + bc
__global__ __launch_bounds__(256) void reduce_kernel(const float* __restrict__ partials,
                                                     const float* __restrict__ bc,
                                                     float* __restrict__ out) {
    int idx = blockIdx.x * 256 + threadIdx.x; // 0..4095
    float s = bc[idx & 63];
#pragma unroll 8
    for (int b = 0; b < 256; b++) s += partials[b * 4096 + idx];
    out[idx] = s;
}

// ---------------------------------------------------------------------------
extern "C" void kernel_launch(void* const* d_in, const int* in_sizes, int n_in,
                              void* d_out, int out_size, void* d_ws, size_t ws_size,
                              hipStream_t stream) {
    const float* states     = (const float*)d_in[0]; // [64][512][1024]
    const float* output_set = (const float*)d_in[1]; // [64][1024]
    const float* Wo         = (const float*)d_in[2]; // [2048][1024]
    const float* bo         = (const float*)d_in[3]; // [1024]
    const float* Wc         = (const float*)d_in[4]; // [65536][64]
    const float* bc         = (const float*)d_in[5]; // [64]
    float* out = (float*)d_out;                      // [64][64]

    char* ws = (char*)d_ws;
    float*          attnf = (float*)ws;                                       // 8 MB
    unsigned short* attnb = (unsigned short*)(ws + (8u  << 20));              // 4 MB
    unsigned short* mixb  = (unsigned short*)(ws + (12u << 20));              // 8 MB
    unsigned short* tb    = (unsigned short*)(ws + (20u << 20));              // 8 MB
    unsigned short* woT   = (unsigned short*)(ws + (28u << 20));              // 4 MB
    unsigned short* osb   = (unsigned short*)(ws + (32u << 20));              // 128 KB
    unsigned short* wcT   = (unsigned short*)(ws + (32u << 20) + (1u << 18)); // 8 MB
    float*          parts = (float*)(ws + (41u << 20));                       // 4 MB

    cvt_kernel<<<dim3(IOdim * Hdim / 256), dim3(256), 0, stream>>>(output_set, osb, IOdim * Hdim);
    transpose_cvt<<<dim3(Hdim / 32, 2048 / 32), dim3(32, 8), 0, stream>>>(Wo, woT, 2048, Hdim);
    transpose_cvt<<<dim3(64 / 32, 65536 / 32), dim3(32, 8), 0, stream>>>(Wc, wcT, 65536, 64);
    scores_kernel<<<dim3(Sdim / 64, Nbat), dim3(256), 0, stream>>>(states, osb, attnf);
    softmax_kernel<<<dim3(Nbat * IOdim / 4), dim3(256), 0, stream>>>(attnf, attnb);
    mix_kernel<<<dim3(Hdim / 64, Nbat), dim3(256), 0, stream>>>(states, attnb, mixb);
    out_gemm<<<dim3(Hdim / 128, Nbat * IOdim / 64), dim3(256), 0, stream>>>(mixb, osb, woT, bo, tb);
    final_gemm<<<dim3(256), dim3(256), 0, stream>>>(tb, wcT, parts);
    reduce_kernel<<<dim3(16), dim3(256), 0, stream>>>(parts, bc, out);
}

// Round 3
// 344.485 us; speedup vs baseline: 1.1078x; 1.1078x over previous
//
#include <hip/hip_runtime.h>
#include <hip/hip_bf16.h>

// Problem: N=64 batches, IO=64, H=1024, S=512
#define IOdim 64
#define Hdim  1024
#define Sdim  512
#define Nbat  64

typedef __bf16 bf16x8_t __attribute__((ext_vector_type(8)));
typedef float  f32x4_t  __attribute__((ext_vector_type(4)));

#define MFMA16(a, b, c) __builtin_amdgcn_mfma_f32_16x16x32_bf16((a), (b), (c), 0, 0, 0)

__device__ __forceinline__ unsigned short f2bf(float f) {
    return __builtin_bit_cast(unsigned short, (__bf16)f);
}
__device__ __forceinline__ bf16x8_t cvt8(float4 p0, float4 p1) {
    bf16x8_t b;
    b[0] = (__bf16)p0.x; b[1] = (__bf16)p0.y; b[2] = (__bf16)p0.z; b[3] = (__bf16)p0.w;
    b[4] = (__bf16)p1.x; b[5] = (__bf16)p1.y; b[6] = (__bf16)p1.z; b[7] = (__bf16)p1.w;
    return b;
}
// async 16B global->LDS (direct-to-shared DMA, vmcnt-tracked)
__device__ __forceinline__ void async16(const void* g, void* l) {
    __builtin_amdgcn_global_load_lds(
        (const __attribute__((address_space(1))) void*)g,
        (__attribute__((address_space(3))) void*)l, 16, 0, 0);
}

// ---------------------------------------------------------------------------
__global__ __launch_bounds__(256) void cvt_kernel(const float* __restrict__ in,
                                                  unsigned short* __restrict__ outp,
                                                  int nElem) {
    int idx = blockIdx.x * 256 + threadIdx.x;
    if (idx < nElem) outp[idx] = f2bf(in[idx]);
}

__global__ __launch_bounds__(256) void transpose_cvt(const float* __restrict__ in,
                                                     unsigned short* __restrict__ outp,
                                                     int R, int C) {
    __shared__ float tile[32][33];
    int c0 = blockIdx.x * 32, r0 = blockIdx.y * 32;
    int tx = threadIdx.x, ty = threadIdx.y; // 32 x 8
#pragma unroll
    for (int i = 0; i < 4; i++) {
        int r = ty + i * 8;
        tile[r][tx] = in[(size_t)(r0 + r) * C + c0 + tx];
    }
    __syncthreads();
#pragma unroll
    for (int i = 0; i < 4; i++) {
        int r = ty + i * 8;
        outp[(size_t)(c0 + r) * R + r0 + tx] = f2bf(tile[tx][r]);
    }
}

// ---------------------------------------------------------------------------
// scores: attn[n][i][s] = sum_h output_set[i][h] * states[n][s][h]
// Register double-buffered: states fp32 stream + osb fragments prefetched one
// 32-k chunk ahead so global latency overlaps MFMA.
__global__ __launch_bounds__(256) void scores_kernel(const float* __restrict__ states,
                                                     const unsigned short* __restrict__ osb,
                                                     float* __restrict__ attnf) {
    int n = blockIdx.y;
    int tid = threadIdx.x, lane = tid & 63, g = tid >> 6;
    int col = lane & 15, quad = lane >> 4;
    int s = blockIdx.x * 64 + g * 16 + col;
    const float* srow = states + (size_t)(n * Sdim + s) * Hdim + quad * 8;
    const unsigned short* ap = osb + (size_t)col * Hdim + quad * 8;
    f32x4_t acc0 = {0,0,0,0}, acc1 = {0,0,0,0}, acc2 = {0,0,0,0}, acc3 = {0,0,0,0};
    float4 c0 = *(const float4*)(srow);
    float4 c1 = *(const float4*)(srow + 4);
    bf16x8_t A0 = *(const bf16x8_t*)(ap);
    bf16x8_t A1 = *(const bf16x8_t*)(ap + 16 * Hdim);
    bf16x8_t A2 = *(const bf16x8_t*)(ap + 32 * Hdim);
    bf16x8_t A3 = *(const bf16x8_t*)(ap + 48 * Hdim);
#pragma unroll 4
    for (int kc = 0; kc < Hdim - 32; kc += 32) {
        int kn = kc + 32;
        float4 n0 = *(const float4*)(srow + kn);
        float4 n1 = *(const float4*)(srow + kn + 4);
        bf16x8_t N0 = *(const bf16x8_t*)(ap + kn);
        bf16x8_t N1 = *(const bf16x8_t*)(ap + 16 * Hdim + kn);
        bf16x8_t N2 = *(const bf16x8_t*)(ap + 32 * Hdim + kn);
        bf16x8_t N3 = *(const bf16x8_t*)(ap + 48 * Hdim + kn);
        bf16x8_t b = cvt8(c0, c1);
        acc0 = MFMA16(A0, b, acc0);
        acc1 = MFMA16(A1, b, acc1);
        acc2 = MFMA16(A2, b, acc2);
        acc3 = MFMA16(A3, b, acc3);
        c0 = n0; c1 = n1; A0 = N0; A1 = N1; A2 = N2; A3 = N3;
    }
    {   // peeled last chunk
        bf16x8_t b = cvt8(c0, c1);
        acc0 = MFMA16(A0, b, acc0);
        acc1 = MFMA16(A1, b, acc1);
        acc2 = MFMA16(A2, b, acc2);
        acc3 = MFMA16(A3, b, acc3);
    }
    f32x4_t accs[4] = {acc0, acc1, acc2, acc3};
    float* ob = attnf + (size_t)(n * IOdim) * Sdim + blockIdx.x * 64 + g * 16 + col;
#pragma unroll
    for (int ai = 0; ai < 4; ai++)
#pragma unroll
        for (int r = 0; r < 4; r++) {
            int i = ai * 16 + quad * 4 + r;
            ob[i * Sdim] = accs[ai][r];
        }
}

// ---------------------------------------------------------------------------
__global__ __launch_bounds__(256) void softmax_kernel(const float* __restrict__ attnf,
                                                      unsigned short* __restrict__ attnb) {
    int row = blockIdx.x * 4 + (threadIdx.x >> 6);
    int lane = threadIdx.x & 63;
    const float* p = attnf + (size_t)row * Sdim + lane * 8;
    float4 v0 = ((const float4*)p)[0];
    float4 v1 = ((const float4*)p)[1];
    float v[8] = {v0.x, v0.y, v0.z, v0.w, v1.x, v1.y, v1.z, v1.w};
    float m = v[0];
#pragma unroll
    for (int j = 1; j < 8; j++) m = fmaxf(m, v[j]);
#pragma unroll
    for (int off = 32; off > 0; off >>= 1) m = fmaxf(m, __shfl_xor(m, off));
    float sum = 0.f;
#pragma unroll
    for (int j = 0; j < 8; j++) { v[j] = __expf(v[j] - m); sum += v[j]; }
#pragma unroll
    for (int off = 32; off > 0; off >>= 1) sum += __shfl_xor(sum, off);
    float inv = 1.0f / sum;
    union { unsigned short u[8]; uint4 q; } res;
#pragma unroll
    for (int j = 0; j < 8; j++) res.u[j] = f2bf(v[j] * inv);
    *(uint4*)(attnb + (size_t)row * Sdim + lane * 8) = res.q;
}

// ---------------------------------------------------------------------------
// mix[n][i][h] = sum_s attn[n][i][s] * states[n][s][h]
// statesT chunk through LDS; next chunk's 16 strided loads prefetched into
// registers before the barrier so they fly during the MFMA phase.
__global__ __launch_bounds__(256) void mix_kernel(const float* __restrict__ states,
                                                  const unsigned short* __restrict__ attnb,
                                                  unsigned short* __restrict__ mixb) {
    __shared__ unsigned short Tlds[64 * 72]; // [h 64][s 64] stride 72
    int n = blockIdx.y, h0 = blockIdx.x * 64;
    int tid = threadIdx.x, lane = tid & 63, g = tid >> 6;
    int col = lane & 15, quad = lane >> 4;
    f32x4_t acc0 = {0,0,0,0}, acc1 = {0,0,0,0}, acc2 = {0,0,0,0}, acc3 = {0,0,0,0};
    const unsigned short* ap = attnb + (size_t)(n * IOdim + col) * Sdim + quad * 8;
    const float* sbase = states + (size_t)n * Sdim * Hdim + h0 + lane;
    float cur[16];
#pragma unroll
    for (int rep = 0; rep < 16; rep++) cur[rep] = sbase[(size_t)(g * 16 + rep) * Hdim];
    for (int sc = 0; sc < Sdim; sc += 64) {
        union { unsigned short u[16]; uint4 q[2]; } pk;
#pragma unroll
        for (int rep = 0; rep < 16; rep++) pk.u[rep] = f2bf(cur[rep]);
        if (sc) __syncthreads(); // prev chunk's readers done before overwrite
        *(uint4*)(Tlds + lane * 72 + g * 16)     = pk.q[0];
        *(uint4*)(Tlds + lane * 72 + g * 16 + 8) = pk.q[1];
        if (sc + 64 < Sdim) {
#pragma unroll
            for (int rep = 0; rep < 16; rep++)
                cur[rep] = sbase[(size_t)(sc + 64 + g * 16 + rep) * Hdim];
        }
        __syncthreads();
#pragma unroll
        for (int ks = 0; ks < 64; ks += 32) {
            bf16x8_t b  = *(const bf16x8_t*)(Tlds + (g * 16 + col) * 72 + ks + quad * 8);
            bf16x8_t a0 = *(const bf16x8_t*)(ap + sc + ks);
            bf16x8_t a1 = *(const bf16x8_t*)(ap + 16 * Sdim + sc + ks);
            bf16x8_t a2 = *(const bf16x8_t*)(ap + 32 * Sdim + sc + ks);
            bf16x8_t a3 = *(const bf16x8_t*)(ap + 48 * Sdim + sc + ks);
            acc0 = MFMA16(a0, b, acc0);
            acc1 = MFMA16(a1, b, acc1);
            acc2 = MFMA16(a2, b, acc2);
            acc3 = MFMA16(a3, b, acc3);
        }
    }
    f32x4_t accs[4] = {acc0, acc1, acc2, acc3};
    int h = h0 + g * 16 + col;
#pragma unroll
    for (int ai = 0; ai < 4; ai++)
#pragma unroll
        for (int r = 0; r < 4; r++) {
            int i = ai * 16 + quad * 4 + r;
            mixb[(size_t)(n * IOdim + i) * Hdim + h] = f2bf(accs[ai][r]);
        }
}

// ---------------------------------------------------------------------------
// out_gemm: m97-style 128x128 tile, BK=32, A+B staged via global_load_lds.
// M=4096 (r=n*64+io), N=1024 (h), K=2048; A switches mixb->osb at k=1024.
__global__ __launch_bounds__(256) void out_gemm(const unsigned short* __restrict__ mixb,
                                                const unsigned short* __restrict__ osb,
                                                const unsigned short* __restrict__ woT,
                                                const float* __restrict__ bo,
                                                unsigned short* __restrict__ tb) {
    __shared__ unsigned short Ald[128 * 32];
    __shared__ unsigned short Bld[128 * 32];
    int h0 = blockIdx.x * 128, r0 = blockIdx.y * 128;
    int tid = threadIdx.x, lane = tid & 63, w = tid >> 6;
    int col = lane & 15, quad = lane >> 4;
    int wx = w & 1, wy = w >> 1;
    int rowA = tid >> 2, seg = tid & 3; // staging: rows 0..63 (+64 for 2nd load)
    f32x4_t acc[4][4] = {};
    const unsigned short* m1 = mixb + (size_t)(r0 + rowA) * Hdim + seg * 8;
    const unsigned short* m2 = mixb + (size_t)(r0 + rowA + 64) * Hdim + seg * 8;
    const unsigned short* o1 = osb + (size_t)rowA * Hdim + seg * 8; // rowA&63==rowA, (rowA+64)&63==rowA
    const unsigned short* w1 = woT + (size_t)(h0 + rowA) * 2048 + seg * 8;
    const unsigned short* w2 = woT + (size_t)(h0 + rowA + 64) * 2048 + seg * 8;
    unsigned short* lA1 = Ald + (size_t)tid * 8;
    unsigned short* lA2 = Ald + (size_t)(tid + 256) * 8;
    unsigned short* lB1 = Bld + (size_t)tid * 8;
    unsigned short* lB2 = Bld + (size_t)(tid + 256) * 8;
    for (int kc = 0; kc < 2048; kc += 32) {
        if (kc < 1024) {
            async16(m1 + kc, lA1);
            async16(m2 + kc, lA2);
        } else {
            async16(o1 + (kc - 1024), lA1);
            async16(o1 + (kc - 1024), lA2); // rows r and r+64 share osb row (r%64)
        }
        async16(w1 + kc, lB1);
        async16(w2 + kc, lB2);
        __syncthreads();
        bf16x8_t af[4], bfr[4];
#pragma unroll
        for (int mi = 0; mi < 4; mi++)
            af[mi] = *(const bf16x8_t*)(Ald + (wy * 64 + mi * 16 + col) * 32 + quad * 8);
#pragma unroll
        for (int ni = 0; ni < 4; ni++)
            bfr[ni] = *(const bf16x8_t*)(Bld + (wx * 64 + ni * 16 + col) * 32 + quad * 8);
#pragma unroll
        for (int mi = 0; mi < 4; mi++)
#pragma unroll
            for (int ni = 0; ni < 4; ni++)
                acc[mi][ni] = MFMA16(af[mi], bfr[ni], acc[mi][ni]);
        __syncthreads();
    }
    // epilogue: bias + tanh -> bf16
#pragma unroll
    for (int ni = 0; ni < 4; ni++) {
        int h = h0 + wx * 64 + ni * 16 + col;
        float bov = bo[h];
#pragma unroll
        for (int mi = 0; mi < 4; mi++)
#pragma unroll
            for (int r = 0; r < 4; r++) {
                int rr = r0 + wy * 64 + mi * 16 + quad * 4 + r;
                tb[(size_t)rr * Hdim + h] = f2bf(tanhf(acc[mi][ni][r] + bov));
            }
    }
}

// ---------------------------------------------------------------------------
// final: partial[blk][n][j] = sum_{k in 256-chunk} t[n][k] * Wc[k][j]
// 256 blocks split K=65536; register double-buffered fragment loads.
__global__ __launch_bounds__(256) void final_gemm(const unsigned short* __restrict__ tb,
                                                  const unsigned short* __restrict__ wcT,
                                                  float* __restrict__ partials) {
    int kc0 = blockIdx.x * 256;
    int tid = threadIdx.x, lane = tid & 63, g = tid >> 6;
    int col = lane & 15, quad = lane >> 4;
    f32x4_t acc0 = {0,0,0,0}, acc1 = {0,0,0,0}, acc2 = {0,0,0,0}, acc3 = {0,0,0,0};
    const unsigned short* ap = tb + (size_t)col * 65536 + kc0 + quad * 8;
    const unsigned short* bp = wcT + (size_t)(g * 16 + col) * 65536 + kc0 + quad * 8;
    bf16x8_t B  = *(const bf16x8_t*)(bp);
    bf16x8_t A0 = *(const bf16x8_t*)(ap);
    bf16x8_t A1 = *(const bf16x8_t*)(ap + (size_t)16 * 65536);
    bf16x8_t A2 = *(const bf16x8_t*)(ap + (size_t)32 * 65536);
    bf16x8_t A3 = *(const bf16x8_t*)(ap + (size_t)48 * 65536);
#pragma unroll
    for (int kc = 0; kc < 256 - 32; kc += 32) {
        int kn = kc + 32;
        bf16x8_t Bn  = *(const bf16x8_t*)(bp + kn);
        bf16x8_t N0 = *(const bf16x8_t*)(ap + kn);
        bf16x8_t N1 = *(const bf16x8_t*)(ap + (size_t)16 * 65536 + kn);
        bf16x8_t N2 = *(const bf16x8_t*)(ap + (size_t)32 * 65536 + kn);
        bf16x8_t N3 = *(const bf16x8_t*)(ap + (size_t)48 * 65536 + kn);
        acc0 = MFMA16(A0, B, acc0);
        acc1 = MFMA16(A1, B, acc1);
        acc2 = MFMA16(A2, B, acc2);
        acc3 = MFMA16(A3, B, acc3);
        B = Bn; A0 = N0; A1 = N1; A2 = N2; A3 = N3;
    }
    acc0 = MFMA16(A0, B, acc0);
    acc1 = MFMA16(A1, B, acc1);
    acc2 = MFMA16(A2, B, acc2);
    acc3 = MFMA16(A3, B, acc3);
    f32x4_t accs[4] = {acc0, acc1, acc2, acc3};
    int j = g * 16 + col;
    float* pb = partials + blockIdx.x * 4096;
#pragma unroll
    for (int ai = 0; ai < 4; ai++)
#pragma unroll
        for (int r = 0; r < 4; r++) {
            int nn = ai * 16 + quad * 4 + r;
            pb[nn * 64 + j] = accs[ai][r];
        }
}

__global__ __launch_bounds__(256) void reduce_kernel(const float* __restrict__ partials,
                                                     const float* __restrict__ bc,
                                                     float* __restrict__ out) {
    int idx = blockIdx.x * 256 + threadIdx.x; // 0..4095
    float s = bc[idx & 63];
#pragma unroll 8
    for (int b = 0; b < 256; b++) s += partials[b * 4096 + idx];
    out[idx] = s;
}

// ---------------------------------------------------------------------------
extern "C" void kernel_launch(void* const* d_in, const int* in_sizes, int n_in,
                              void* d_out, int out_size, void* d_ws, size_t ws_size,
                              hipStream_t stream) {
    const float* states     = (const float*)d_in[0]; // [64][512][1024]
    const float* output_set = (const float*)d_in[1]; // [64][1024]
    const float* Wo         = (const float*)d_in[2]; // [2048][1024]
    const float* bo         = (const float*)d_in[3]; // [1024]
    const float* Wc         = (const float*)d_in[4]; // [65536][64]
    const float* bc         = (const float*)d_in[5]; // [64]
    float* out = (float*)d_out;                      // [64][64]

    char* ws = (char*)d_ws;
    float*          attnf = (float*)ws;                                       // 8 MB
    unsigned short* attnb = (unsigned short*)(ws + (8u  << 20));              // 4 MB
    unsigned short* mixb  = (unsigned short*)(ws + (12u << 20));              // 8 MB
    unsigned short* tb    = (unsigned short*)(ws + (20u << 20));              // 8 MB
    unsigned short* woT   = (unsigned short*)(ws + (28u << 20));              // 4 MB
    unsigned short* osb   = (unsigned short*)(ws + (32u << 20));              // 128 KB
    unsigned short* wcT   = (unsigned short*)(ws + (32u << 20) + (1u << 18)); // 8 MB
    float*          parts = (float*)(ws + (41u << 20));                       // 4 MB

    cvt_kernel<<<dim3(IOdim * Hdim / 256), dim3(256), 0, stream>>>(output_set, osb, IOdim * Hdim);
    transpose_cvt<<<dim3(Hdim / 32, 2048 / 32), dim3(32, 8), 0, stream>>>(Wo, woT, 2048, Hdim);
    transpose_cvt<<<dim3(64 / 32, 65536 / 32), dim3(32, 8), 0, stream>>>(Wc, wcT, 65536, 64);
    scores_kernel<<<dim3(Sdim / 64, Nbat), dim3(256), 0, stream>>>(states, osb, attnf);
    softmax_kernel<<<dim3(Nbat * IOdim / 4), dim3(256), 0, stream>>>(attnf, attnb);
    mix_kernel<<<dim3(Hdim / 64, Nbat), dim3(256), 0, stream>>>(states, attnb, mixb);
    out_gemm<<<dim3(Hdim / 128, Nbat * IOdim / 128), dim3(256), 0, stream>>>(mixb, osb, woT, bo, tb);
    final_gemm<<<dim3(256), dim3(256), 0, stream>>>(tb, wcT, parts);
    reduce_kernel<<<dim3(16), dim3(256), 0, stream>>>(parts, bc, out);
}